// Round 5
// baseline (415.002 us; speedup 1.0000x reference)
//
#include <hip/hip_runtime.h>
#include <hip/hip_bf16.h>
#include <stdint.h>

#define B_ 2
#define S_ 1024
#define D_ 2048
#define H_ 16
#define F_ 8192
#define DH_ 128
#define M_ 2048  // B*S

typedef unsigned short u16;
typedef __attribute__((ext_vector_type(8))) short short8;
typedef __attribute__((ext_vector_type(4))) float f32x4;
typedef __attribute__((ext_vector_type(2))) float f32x2;
typedef __attribute__((ext_vector_type(2))) unsigned short u16x2;

__device__ __forceinline__ u16 f2bf(float f) {
  union { float f; uint32_t u; } c; c.f = f;
  uint32_t r = c.u + 0x7FFFu + ((c.u >> 16) & 1u);
  return (u16)(r >> 16);
}

__device__ __forceinline__ void gload16(const void* g, void* l) {
  __builtin_amdgcn_global_load_lds((const __attribute__((address_space(1))) void*)g,
                                   (__attribute__((address_space(3))) void*)l, 16, 0, 0);
}

__device__ __forceinline__ float clipa(float a) {
  return fminf(0.2f, fmaxf(-0.2f, a));
}

__device__ __forceinline__ float gelu_f(float x) {
  float z = 0.7978845608028654f * (x + 0.044715f * x * x * x);
  z = fminf(10.f, fmaxf(-10.f, z));
  float e = __expf(2.f * z);
  return 0.5f * x * (1.f + (e - 1.f) / (e + 1.f));
}

// ---------------- f32 -> bf16 vector convert ----------------
__global__ __launch_bounds__(256) void k_cvt(const float* __restrict__ s,
                                             u16* __restrict__ d, int n8) {
  int i = blockIdx.x * 256 + threadIdx.x;
  if (i >= n8) return;
  f32x4 a = *(const f32x4*)(s + (size_t)i * 8);
  f32x4 b = *(const f32x4*)(s + (size_t)i * 8 + 4);
  short8 o;
  o[0] = (short)f2bf(a[0]); o[1] = (short)f2bf(a[1]);
  o[2] = (short)f2bf(a[2]); o[3] = (short)f2bf(a[3]);
  o[4] = (short)f2bf(b[0]); o[5] = (short)f2bf(b[1]);
  o[6] = (short)f2bf(b[2]); o[7] = (short)f2bf(b[3]);
  *(short8*)(d + (size_t)i * 8) = o;
}

// ---------------- CenterNorm ----------------
__global__ __launch_bounds__(256) void k_centernorm(const float* __restrict__ x,
                                                    const float* __restrict__ g,
                                                    const float* __restrict__ bb,
                                                    float* __restrict__ of,
                                                    u16* __restrict__ ob) {
  const int row = blockIdx.x;
  const int t = threadIdx.x;
  const float* xr = x + (size_t)row * D_;
  f32x4 v0 = *(const f32x4*)(xr + t * 8);
  f32x4 v1 = *(const f32x4*)(xr + t * 8 + 4);
  float s = v0[0] + v0[1] + v0[2] + v0[3] + v1[0] + v1[1] + v1[2] + v1[3];
#pragma unroll
  for (int off = 1; off < 64; off <<= 1) s += __shfl_xor(s, off);
  __shared__ float red[4];
  if ((t & 63) == 0) red[t >> 6] = s;
  __syncthreads();
  const float mu = (red[0] + red[1] + red[2] + red[3]) * (1.0f / D_);
  const float CNS = (float)D_ / (float)(D_ - 1);
  f32x4 g0 = *(const f32x4*)(g + t * 8);
  f32x4 g1 = *(const f32x4*)(g + t * 8 + 4);
  f32x4 b0 = *(const f32x4*)(bb + t * 8);
  f32x4 b1 = *(const f32x4*)(bb + t * 8 + 4);
  f32x4 y0, y1;
  short8 yb;
#pragma unroll
  for (int i = 0; i < 4; i++) {
    y0[i] = g0[i] * (CNS * (v0[i] - mu)) + b0[i];
    y1[i] = g1[i] * (CNS * (v1[i] - mu)) + b1[i];
  }
#pragma unroll
  for (int i = 0; i < 4; i++) { yb[i] = (short)f2bf(y0[i]); yb[4 + i] = (short)f2bf(y1[i]); }
  float* orow = of + (size_t)row * D_;
  *(f32x4*)(orow + t * 8) = y0;
  *(f32x4*)(orow + t * 8 + 4) = y1;
  *(short8*)(ob + (size_t)row * D_ + t * 8) = yb;
}

// ---------------- l2norm q,k + head reorder; v convert ----------------
__global__ __launch_bounds__(256) void k_l2norm(const float* __restrict__ q,
                                                const float* __restrict__ k,
                                                const float* __restrict__ v,
                                                u16* __restrict__ qn,
                                                u16* __restrict__ kn,
                                                u16* __restrict__ vn) {
  const int gw = blockIdx.x * 4 + (threadIdx.x >> 6);
  const int l = threadIdx.x & 63;
  const int h = gw & (H_ - 1);
  const int s = (gw >> 4) & (S_ - 1);
  const int b = gw >> 14;
  const size_t src = ((size_t)(b * S_ + s)) * D_ + h * DH_ + l * 2;
  const size_t dst = (((size_t)(b * H_ + h)) * S_ + s) * DH_ + l * 2;
  {
    f32x2 xv = *(const f32x2*)(q + src);
    float ss = xv[0] * xv[0] + xv[1] * xv[1];
#pragma unroll
    for (int off = 1; off < 64; off <<= 1) ss += __shfl_xor(ss, off);
    float sc = 1.f / (sqrtf(ss) + 1e-6f);
    u16x2 o; o[0] = f2bf(xv[0] * sc); o[1] = f2bf(xv[1] * sc);
    *(u16x2*)(qn + dst) = o;
  }
  {
    f32x2 xv = *(const f32x2*)(k + src);
    float ss = xv[0] * xv[0] + xv[1] * xv[1];
#pragma unroll
    for (int off = 1; off < 64; off <<= 1) ss += __shfl_xor(ss, off);
    float sc = 1.f / (sqrtf(ss) + 1e-6f);
    u16x2 o; o[0] = f2bf(xv[0] * sc); o[1] = f2bf(xv[1] * sc);
    *(u16x2*)(kn + dst) = o;
  }
  {
    f32x2 xv = *(const f32x2*)(v + src);
    u16x2 o; o[0] = f2bf(xv[0]); o[1] = f2bf(xv[1]);
    *(u16x2*)(vn + dst) = o;
  }
}

// ============ 256x256 GEMM, 4 phases/K-tile, spread staging, counted vmcnt ============
// C[M,N] = A[M,K]*Bt[N,K]^T. 512 thr = 8 waves (wr in {0,1}, wc in {0..3}), BK=64.
// LDS 128KB: 2 bufs x (A 256x64 | B 256x64) bf16, row-major 128B rows, XOR swizzle
// byte ^= (row&7)<<4 (write side via pre-swizzled global source: involution both sides).
// Wave M-map: phase q computes A rows q*64 + wr*32 + mi*16 -> phase q consumes A-quarter q.
// Stage order for tile t+1 (at tile t's phases 0-3): Bh0, Bh1, Ah0, Ah1 (2 loads each).
// Waits: after ph1 MFMA vmcnt(4) [forces Ah1 of tile t, needed ph2; 2-phase lead],
//        after ph3 MFMA vmcnt(2) [forces Bh0,Bh1,Ah0 of t+1; 3-4 phase lead].
// Never drains to 0 mid-stream; all cross-wave RAW/WAR fenced by vmcnt-then-barrier.
// EPI 0: outf=acc+bias ; 2: outb=bf16(gelu(acc+bias)) ; 3: outf=acc (raw partial)
template <int EPI>
__device__ __forceinline__ void gemm256_core(const u16* __restrict__ A,
                                             const u16* __restrict__ Bt,
                                             const float* __restrict__ bias,
                                             float* __restrict__ outf,
                                             u16* __restrict__ outb,
                                             int N, int K, int kbase, int nk,
                                             int m0, int n0) {
  __shared__ char lds[2][65536];  // [buf][A 32KB | B 32KB]
  const int t = threadIdx.x;
  const int l = t & 63, w = t >> 6;
  const int wr = w >> 2, wc = w & 3;
  const int l15 = l & 15, lhi = l >> 4;
  const int sw = (l15 & 7) << 4;

  // stage one half (region 0=A,1=B; half 0/1) of K-tile kt into buf kt&1
  auto stage = [&](int region, int half, int kt) {
#pragma unroll
    for (int j = 0; j < 2; j++) {
      const int pl = half * 16384 + j * 8192 + t * 16;  // byte offset within region
      const int row = pl >> 7;
      const int scol = (pl & 127) ^ ((row & 7) << 4);   // pre-swizzled source col
      const int grow = (region ? n0 : m0) + row;
      const char* src = (const char*)(region ? Bt : A) +
                        (size_t)grow * (size_t)(K * 2) +
                        (size_t)((kbase + kt * 64) * 2 + scol);
      gload16(src, &lds[kt & 1][region * 32768 + pl]);
    }
  };

  f32x4 acc[8][4] = {};

  // prologue: full tile 0
  stage(1, 0, 0); stage(1, 1, 0); stage(0, 0, 0); stage(0, 1, 0);
  asm volatile("s_waitcnt vmcnt(0)" ::: "memory");
  __builtin_amdgcn_s_barrier();
  __builtin_amdgcn_sched_barrier(0);

  for (int kt = 0; kt < nk; ++kt) {
    const int buf = kt & 1;
    const bool more = (kt + 1 < nk);
    const char* Ab = &lds[buf][0];
    const char* Bb = &lds[buf][32768];
    short8 bf[4][2];
#pragma unroll
    for (int ni = 0; ni < 4; ni++)
#pragma unroll
      for (int ks = 0; ks < 2; ks++) {
        const int r = wc * 64 + ni * 16 + l15;
        bf[ni][ks] = *(const short8*)(Bb + r * 128 + ((ks * 64 + lhi * 16) ^ sw));
      }
#pragma unroll
    for (int q = 0; q < 4; q++) {
      short8 aq[2][2];
#pragma unroll
      for (int mi = 0; mi < 2; mi++)
#pragma unroll
        for (int ks = 0; ks < 2; ks++) {
          const int r = q * 64 + wr * 32 + mi * 16 + l15;
          aq[mi][ks] = *(const short8*)(Ab + r * 128 + ((ks * 64 + lhi * 16) ^ sw));
        }
      if (more) stage(q < 2 ? 1 : 0, q & 1, kt + 1);
      asm volatile("s_waitcnt lgkmcnt(0)" ::: "memory");
      __builtin_amdgcn_sched_barrier(0);
      __builtin_amdgcn_s_setprio(1);
#pragma unroll
      for (int mi = 0; mi < 2; mi++)
#pragma unroll
        for (int ni = 0; ni < 4; ni++)
#pragma unroll
          for (int ks = 0; ks < 2; ks++)
            acc[q * 2 + mi][ni] = __builtin_amdgcn_mfma_f32_16x16x32_bf16(
                aq[mi][ks], bf[ni][ks], acc[q * 2 + mi][ni], 0, 0, 0);
      __builtin_amdgcn_s_setprio(0);
      if (q == 1) {
        if (more) { asm volatile("s_waitcnt vmcnt(4)" ::: "memory"); }
        else      { asm volatile("s_waitcnt vmcnt(0)" ::: "memory"); }
        __builtin_amdgcn_s_barrier();
        __builtin_amdgcn_sched_barrier(0);
      }
      if (q == 3) {
        asm volatile("s_waitcnt vmcnt(2)" ::: "memory");
        __builtin_amdgcn_s_barrier();
        __builtin_amdgcn_sched_barrier(0);
      }
    }
  }

#pragma unroll
  for (int ni = 0; ni < 4; ni++) {
    const int col = n0 + wc * 64 + ni * 16 + l15;
    const float bcol = (EPI == 3) ? 0.f : bias[col];
#pragma unroll
    for (int ai = 0; ai < 8; ai++) {
      const int row = m0 + (ai >> 1) * 64 + wr * 32 + (ai & 1) * 16 + lhi * 4;
#pragma unroll
      for (int j = 0; j < 4; j++) {
        const float v = acc[ai][ni][j] + bcol;
        const size_t idx = (size_t)(row + j) * N + col;
        if (EPI == 0) outf[idx] = v;
        else if (EPI == 2) outb[idx] = f2bf(gelu_f(v));
        else outf[idx] = v;
      }
    }
  }
}

// XCD-aware swizzle of the 2D (x,y) grid; nwg must be %8==0 (all ours are)
__device__ __forceinline__ void xcd_swz(int gx, int gy, int& bx, int& by) {
  const int nwg = gx * gy;
  const int bid = blockIdx.y * gx + blockIdx.x;
  const int s = (bid & 7) * (nwg >> 3) + (bid >> 3);
  bx = s % gx;
  by = s / gx;
}

__global__ __launch_bounds__(512, 2) void k_qkv256(const u16* A, const u16* W,
                                                   const float* b0, const float* b1,
                                                   const float* b2, float* o0, float* o1,
                                                   float* o2) {
  const int z = blockIdx.z;
  const u16* Bt = W + (size_t)z * 4194304;
  const float* bias = z == 0 ? b0 : (z == 1 ? b1 : b2);
  float* out = z == 0 ? o0 : (z == 1 ? o1 : o2);
  int bx, by; xcd_swz(8, 8, bx, by);
  gemm256_core<0>(A, Bt, bias, out, nullptr, D_, D_, 0, 32, by * 256, bx * 256);
}

__global__ __launch_bounds__(512, 2) void k_ffn1_256(const u16* A, const u16* Bt,
                                                     const float* bias, u16* outb) {
  int bx, by; xcd_swz(32, 8, bx, by);
  gemm256_core<2>(A, Bt, bias, nullptr, outb, F_, D_, 0, 32, by * 256, bx * 256);
}

__global__ __launch_bounds__(512, 2) void k_ffn2_256(const u16* A, const u16* Bt, float* P) {
  int bx, by; xcd_swz(8, 8, bx, by);
  gemm256_core<3>(A, Bt, nullptr, P + (size_t)blockIdx.z * M_ * D_, nullptr, D_, F_,
                  blockIdx.z * 2048, 32, by * 256, bx * 256);
}

// ---------------- 128x128 2-phase GEMM (o-proj: EPI1 residual) ----------------
__device__ __forceinline__ void gemm128_res(const u16* __restrict__ A,
                                            const u16* __restrict__ Bt,
                                            const float* __restrict__ bias,
                                            const float* __restrict__ res,
                                            const float* __restrict__ alpha,
                                            float* __restrict__ outf, int N, int K) {
  __shared__ u16 As[2][128 * 32];
  __shared__ u16 Bs[2][128 * 32];
  const int t = threadIdx.x;
  const int l = t & 63;
  const int w = t >> 6;
  const int wr = w >> 1, wc = w & 1;
  const int l15 = l & 15, lhi = l >> 4;
  const int m0 = blockIdx.y * 128, n0 = blockIdx.x * 128;
  f32x4 acc[4][4] = {};
  const int srow = t >> 2;
  const int scol = (t & 3) * 8;
  const u16* Ag = A + (size_t)(m0 + srow) * K + scol;
  const u16* Ag2 = Ag + (size_t)64 * K;
  const u16* Bg = Bt + (size_t)(n0 + srow) * K + scol;
  const u16* Bg2 = Bg + (size_t)64 * K;
  const int loff = t * 16;
  const int kiters = K / 32;

  gload16(Ag, (char*)As[0] + loff);
  gload16(Ag2, (char*)As[0] + 4096 + loff);
  gload16(Bg, (char*)Bs[0] + loff);
  gload16(Bg2, (char*)Bs[0] + 4096 + loff);
  __syncthreads();

  int cur = 0;
  for (int it = 0; it < kiters; ++it) {
    if (it + 1 < kiters) {
      const int k0 = (it + 1) * 32;
      char* dA = (char*)As[cur ^ 1] + loff;
      char* dB = (char*)Bs[cur ^ 1] + loff;
      gload16(Ag + k0, dA);
      gload16(Ag2 + k0, dA + 4096);
      gload16(Bg + k0, dB);
      gload16(Bg2 + k0, dB + 4096);
    }
    short8 af[4], bfr[4];
#pragma unroll
    for (int i = 0; i < 4; i++)
      af[i] = *(const short8*)(As[cur] + (wr * 64 + i * 16 + l15) * 32 + lhi * 8);
#pragma unroll
    for (int i = 0; i < 4; i++)
      bfr[i] = *(const short8*)(Bs[cur] + (wc * 64 + i * 16 + l15) * 32 + lhi * 8);
#pragma unroll
    for (int mi = 0; mi < 4; mi++)
#pragma unroll
      for (int ni = 0; ni < 4; ni++)
        acc[mi][ni] = __builtin_amdgcn_mfma_f32_16x16x32_bf16(af[mi], bfr[ni], acc[mi][ni], 0, 0, 0);
    __syncthreads();
    cur ^= 1;
  }
#pragma unroll
  for (int ni = 0; ni < 4; ni++) {
    const int col = n0 + wc * 64 + ni * 16 + l15;
    const float bcol = bias[col];
    const float alc = clipa(alpha[col]);
#pragma unroll
    for (int mi = 0; mi < 4; mi++) {
#pragma unroll
      for (int j = 0; j < 4; j++) {
        const int row = m0 + wr * 64 + mi * 16 + lhi * 4 + j;
        const size_t idx = (size_t)row * N + col;
        outf[idx] = res[idx] + alc * (acc[mi][ni][j] + bcol);
      }
    }
  }
}

__global__ __launch_bounds__(256) void k_oproj(const u16* A, const u16* Bt, const float* bias,
                                               const float* res, const float* alpha,
                                               float* outf) {
  gemm128_res(A, Bt, bias, res, alpha, outf, D_, D_);
}

// out = res + clip(alpha)*(sum_z P[z] + bias)
__global__ __launch_bounds__(256) void k_ffn2_combine(const float* __restrict__ P,
                                                      const float* __restrict__ bias,
                                                      const float* __restrict__ res,
                                                      const float* __restrict__ alpha,
                                                      float* __restrict__ out) {
  const int i = blockIdx.x * 256 + threadIdx.x;
  const size_t base = (size_t)i * 8;
  const int col = (int)(base & (D_ - 1));
  const size_t PS = (size_t)M_ * D_;
  f32x4 s0 = {}, s1 = {};
#pragma unroll
  for (int p = 0; p < 4; p++) {
    s0 += *(const f32x4*)(P + p * PS + base);
    s1 += *(const f32x4*)(P + p * PS + base + 4);
  }
  f32x4 b0 = *(const f32x4*)(bias + col);
  f32x4 b1 = *(const f32x4*)(bias + col + 4);
  f32x4 a0 = *(const f32x4*)(alpha + col);
  f32x4 a1 = *(const f32x4*)(alpha + col + 4);
  f32x4 r0 = *(const f32x4*)(res + base);
  f32x4 r1 = *(const f32x4*)(res + base + 4);
  f32x4 o0, o1;
#pragma unroll
  for (int j = 0; j < 4; j++) {
    o0[j] = r0[j] + clipa(a0[j]) * (s0[j] + b0[j]);
    o1[j] = r1[j] + clipa(a1[j]) * (s1[j] + b1[j]);
  }
  *(f32x4*)(out + base) = o0;
  *(f32x4*)(out + base + 4) = o1;
}

// ---------------- attention: cosine attn, causal, online softmax ----------------
__global__ __launch_bounds__(256) void k_attn(const u16* __restrict__ qn,
                                              const u16* __restrict__ kn,
                                              const u16* __restrict__ vn,
                                              const float* __restrict__ tau,
                                              const float* __restrict__ nu,
                                              u16* __restrict__ o) {
  __shared__ u16 Ks[64 * 128];   // row-major [kv][dh], XOR-swizzled
  __shared__ u16 Vt[128 * 64];   // transposed [dh][kv], XOR-swizzled
  __shared__ u16 Pl[4][16][72];  // per-wave P, +8 pad
  const int t = threadIdx.x;
  const int l = t & 63, w = t >> 6;
  const int l15 = l & 15, lhi = l >> 4;
  const int qt = blockIdx.x;
  const int bh = blockIdx.y;
  const int h = bh & (H_ - 1);
  const int b = bh >> 4;
  const size_t hoff = (size_t)bh * S_ * DH_;
  const u16* Qh = qn + hoff;
  const u16* Kh = kn + hoff;
  const u16* Vh = vn + hoff;
  const int q0 = qt * 64;
  const int r0 = q0 + w * 16;
  short8 qf[4];
#pragma unroll
  for (int kk = 0; kk < 4; kk++)
    qf[kk] = *(const short8*)(Qh + (size_t)(r0 + l15) * DH_ + kk * 32 + lhi * 8);
  const float taum = tau[h];
  float mrow[4], lrow[4];
  f32x4 oacc[8] = {};
#pragma unroll
  for (int j = 0; j < 4; j++) { mrow[j] = -1e30f; lrow[j] = 0.f; }

  for (int kv0 = 0; kv0 < q0 + 64; kv0 += 64) {
#pragma unroll
    for (int i = 0; i < 4; i++) {
      const int p = i * 4096 + t * 16;
      const int row = p >> 8;
      const int colb = p & 255;
      const int scolb = colb ^ ((row & 7) << 4);
      gload16((const char*)(Kh + (size_t)(kv0 + row) * DH_) + scolb, (char*)Ks + p);
    }
#pragma unroll
    for (int i = 0; i < 4; i++) {
      const int c0 = w * 8 + i * 32;
      const int r = l;
      short8 vv = *(const short8*)(Vh + (size_t)(kv0 + r) * DH_ + c0);
#pragma unroll
      for (int j = 0; j < 8; j++) {
        const int ba = ((c0 + j) * 128 + r * 2) ^ (((c0 + j) & 7) << 4);
        *(u16*)((char*)Vt + ba) = (u16)vv[j];
      }
    }
    __syncthreads();
    f32x4 st[4] = {};
#pragma unroll
    for (int ks = 0; ks < 4; ks++) {
#pragma unroll
      for (int ct = 0; ct < 4; ct++) {
        const int n = ct * 16 + l15;
        const int ka = (ks * 32 + lhi * 8) * 2;
        short8 kf = *(const short8*)((const char*)Ks + n * 256 + (ka ^ ((n & 7) << 4)));
        st[ct] = __builtin_amdgcn_mfma_f32_16x16x32_bf16(qf[ks], kf, st[ct], 0, 0, 0);
      }
    }
    float pm[4] = {-1e30f, -1e30f, -1e30f, -1e30f};
#pragma unroll
    for (int ct = 0; ct < 4; ct++) {
      const int col = kv0 + ct * 16 + l15;
#pragma unroll
      for (int j = 0; j < 4; j++) {
        const int row = r0 + lhi * 4 + j;
        float s = st[ct][j] * taum;
        s = (col <= row) ? s : -1e30f;
        st[ct][j] = s;
        pm[j] = fmaxf(pm[j], s);
      }
    }
#pragma unroll
    for (int j = 0; j < 4; j++) {
#pragma unroll
      for (int off = 1; off < 16; off <<= 1) pm[j] = fmaxf(pm[j], __shfl_xor(pm[j], off));
    }
    float scl[4], psum[4];
#pragma unroll
    for (int j = 0; j < 4; j++) {
      const float nm = fmaxf(mrow[j], pm[j]);
      scl[j] = __expf(mrow[j] - nm);
      mrow[j] = nm;
      psum[j] = 0.f;
    }
#pragma unroll
    for (int ct = 0; ct < 4; ct++) {
#pragma unroll
      for (int j = 0; j < 4; j++) {
        const float p = __expf(st[ct][j] - mrow[j]);
        psum[j] += p;
        Pl[w][lhi * 4 + j][ct * 16 + l15] = f2bf(p);
      }
    }
#pragma unroll
    for (int j = 0; j < 4; j++) {
#pragma unroll
      for (int off = 1; off < 16; off <<= 1) psum[j] += __shfl_xor(psum[j], off);
      lrow[j] = lrow[j] * scl[j] + psum[j];
    }
#pragma unroll
    for (int nt = 0; nt < 8; nt++) {
#pragma unroll
      for (int j = 0; j < 4; j++) oacc[nt][j] *= scl[j];
    }
#pragma unroll
    for (int ks2 = 0; ks2 < 2; ks2++) {
      short8 pa = *(const short8*)((const char*)&Pl[w][0][0] + l15 * 144 + ks2 * 64 + lhi * 16);
#pragma unroll
      for (int nt = 0; nt < 8; nt++) {
        const int n = nt * 16 + l15;
        const int ba = (n * 128 + (ks2 * 32 + lhi * 8) * 2) ^ ((n & 7) << 4);
        short8 vf = *(const short8*)((const char*)Vt + ba);
        oacc[nt] = __builtin_amdgcn_mfma_f32_16x16x32_bf16(pa, vf, oacc[nt], 0, 0, 0);
      }
    }
    __syncthreads();
  }
  const float num = nu[h];
  float rs[4];
#pragma unroll
  for (int j = 0; j < 4; j++) rs[j] = num / lrow[j];
#pragma unroll
  for (int nt = 0; nt < 8; nt++) {
    const int col = h * DH_ + nt * 16 + l15;
#pragma unroll
    for (int j = 0; j < 4; j++) {
      const int row = r0 + lhi * 4 + j;
      o[((size_t)b * S_ + row) * D_ + col] = f2bf(oacc[nt][j] * rs[j]);
    }
  }
}

// ---------------- launch ----------------
extern "C" void kernel_launch(void* const* d_in, const int* in_sizes, int n_in,
                              void* d_out, int out_size, void* d_ws, size_t ws_size,
                              hipStream_t stream) {
  const float* x    = (const float*)d_in[0];
  const float* ln1g = (const float*)d_in[1];
  const float* ln1b = (const float*)d_in[2];
  const float* wq   = (const float*)d_in[3];
  const float* bq   = (const float*)d_in[4];
  const float* wk   = (const float*)d_in[5];
  const float* bk   = (const float*)d_in[6];
  const float* wv   = (const float*)d_in[7];
  const float* bv   = (const float*)d_in[8];
  const float* wo   = (const float*)d_in[9];
  const float* bo   = (const float*)d_in[10];
  const float* tau  = (const float*)d_in[11];
  const float* nu   = (const float*)d_in[12];
  const float* al1  = (const float*)d_in[13];
  const float* ln2g = (const float*)d_in[14];
  const float* ln2b = (const float*)d_in[15];
  const float* w1   = (const float*)d_in[16];
  const float* b1   = (const float*)d_in[17];
  const float* w2   = (const float*)d_in[18];
  const float* b2   = (const float*)d_in[19];
  const float* al2  = (const float*)d_in[20];

  char* ws = (char*)d_ws;
  u16* WQ = (u16*)(ws + 0);
  u16* WK = (u16*)(ws + 8388608);
  u16* WV = (u16*)(ws + 16777216);
  u16* WO = (u16*)(ws + 25165824);
  u16* W1B = (u16*)(ws + 33554432);
  u16* W2B = (u16*)(ws + 67108864);
  float* AF = (float*)(ws + 100663296);   // centernorm1 f32
  u16*   AB = (u16*)(ws + 117440512);     // centernorm1 bf16
  float* QF = (float*)(ws + 125829120);
  float* KF = (float*)(ws + 142606336);
  float* VF = (float*)(ws + 159383552);
  u16* QN = (u16*)(ws + 176160768);
  u16* KN = (u16*)(ws + 184549376);
  u16* VN = (u16*)(ws + 192937984);
  // reuse after l2norm / attention:
  u16*   OB = (u16*)(ws + 125829120);     // attn out bf16 (over QF)
  u16*   MB = (u16*)(ws + 134217728);     // centernorm2 bf16 (over QF hi half)
  float* X1 = (float*)(ws + 142606336);   // residual1 f32 (over KF)
  float* MF2 = (float*)(ws + 159383552);  // centernorm2 f32 (over VF)
  u16*   HB = (u16*)(ws + 176160768);     // ffn hidden bf16 (over QN..)
  float* P4 = (float*)(ws + 0);           // ffn2 split-K partials, 4x16MB (over dead WQ..W1B)

  // weights -> bf16
  k_cvt<<<2048, 256, 0, stream>>>(wq, WQ, 524288);
  k_cvt<<<2048, 256, 0, stream>>>(wk, WK, 524288);
  k_cvt<<<2048, 256, 0, stream>>>(wv, WV, 524288);
  k_cvt<<<2048, 256, 0, stream>>>(wo, WO, 524288);
  k_cvt<<<8192, 256, 0, stream>>>(w1, W1B, 2097152);
  k_cvt<<<8192, 256, 0, stream>>>(w2, W2B, 2097152);

  // centernorm 1
  k_centernorm<<<M_, 256, 0, stream>>>(x, ln1g, ln1b, AF, AB);

  // qkv projections (WQ/WK/WV contiguous)
  k_qkv256<<<dim3(8, 8, 3), 512, 0, stream>>>(AB, WQ, bq, bk, bv, QF, KF, VF);

  // l2norm + head reorder
  k_l2norm<<<8192, 256, 0, stream>>>(QF, KF, VF, QN, KN, VN);

  // attention
  k_attn<<<dim3(S_ / 64, B_ * H_), 256, 0, stream>>>(QN, KN, VN, tau, nu, OB);

  // output projection + residual (x1 = a + a1*attn) — 128^2 2-phase
  k_oproj<<<dim3(16, 16), 256, 0, stream>>>(OB, WO, bo, AF, al1, X1);

  // centernorm 2
  k_centernorm<<<M_, 256, 0, stream>>>(X1, ln2g, ln2b, MF2, MB);

  // ffn1 (gelu -> bf16)
  k_ffn1_256<<<dim3(32, 8), 512, 0, stream>>>(MB, W1B, b1, HB);

  // ffn2 split-K=4 partials + combine (out = m + a2*(sum+bias))
  k_ffn2_256<<<dim3(8, 8, 4), 512, 0, stream>>>(HB, W2B, P4);
  k_ffn2_combine<<<2048, 256, 0, stream>>>(P4, b2, MF2, al2, (float*)d_out);
}

// Round 6
// 399.732 us; speedup vs baseline: 1.0382x; 1.0382x over previous
//
#include <hip/hip_runtime.h>
#include <hip/hip_bf16.h>
#include <stdint.h>

#define B_ 2
#define S_ 1024
#define D_ 2048
#define H_ 16
#define F_ 8192
#define DH_ 128
#define M_ 2048  // B*S

typedef unsigned short u16;
typedef __attribute__((ext_vector_type(8))) short short8;
typedef __attribute__((ext_vector_type(4))) float f32x4;
typedef __attribute__((ext_vector_type(2))) float f32x2;
typedef __attribute__((ext_vector_type(2))) unsigned short u16x2;

__device__ __forceinline__ u16 f2bf(float f) {
  union { float f; uint32_t u; } c; c.f = f;
  uint32_t r = c.u + 0x7FFFu + ((c.u >> 16) & 1u);
  return (u16)(r >> 16);
}

__device__ __forceinline__ void gload16(const void* g, void* l) {
  __builtin_amdgcn_global_load_lds((const __attribute__((address_space(1))) void*)g,
                                   (__attribute__((address_space(3))) void*)l, 16, 0, 0);
}

__device__ __forceinline__ float clipa(float a) {
  return fminf(0.2f, fmaxf(-0.2f, a));
}

__device__ __forceinline__ float gelu_f(float x) {
  float z = 0.7978845608028654f * (x + 0.044715f * x * x * x);
  z = fminf(10.f, fmaxf(-10.f, z));
  float e = __expf(2.f * z);
  return 0.5f * x * (1.f + (e - 1.f) / (e + 1.f));
}

// ---------------- merged f32 -> bf16 weight convert (dst contiguous) ----------------
// regions (in n8 units): wq,wk,wv,wo = 524288 each; w1,w2 = 2097152 each.
__global__ __launch_bounds__(256) void k_cvt_all(const float* __restrict__ wq,
                                                 const float* __restrict__ wk,
                                                 const float* __restrict__ wv,
                                                 const float* __restrict__ wo,
                                                 const float* __restrict__ w1,
                                                 const float* __restrict__ w2,
                                                 u16* __restrict__ dst) {
  const int gi = blockIdx.x * 256 + threadIdx.x;  // global n8 unit
  const float* s;
  int off;
  if (gi < 2097152) {
    int r = gi >> 19;  // 0..3
    s = r == 0 ? wq : (r == 1 ? wk : (r == 2 ? wv : wo));
    off = gi & 524287;
  } else if (gi < 4194304) {
    s = w1; off = gi - 2097152;
  } else {
    s = w2; off = gi - 4194304;
  }
  f32x4 a = *(const f32x4*)(s + (size_t)off * 8);
  f32x4 b = *(const f32x4*)(s + (size_t)off * 8 + 4);
  short8 o;
  o[0] = (short)f2bf(a[0]); o[1] = (short)f2bf(a[1]);
  o[2] = (short)f2bf(a[2]); o[3] = (short)f2bf(a[3]);
  o[4] = (short)f2bf(b[0]); o[5] = (short)f2bf(b[1]);
  o[6] = (short)f2bf(b[2]); o[7] = (short)f2bf(b[3]);
  *(short8*)(dst + (size_t)gi * 8) = o;
}

// ---------------- CenterNorm ----------------
__global__ __launch_bounds__(256) void k_centernorm(const float* __restrict__ x,
                                                    const float* __restrict__ g,
                                                    const float* __restrict__ bb,
                                                    float* __restrict__ of,
                                                    u16* __restrict__ ob) {
  const int row = blockIdx.x;
  const int t = threadIdx.x;
  const float* xr = x + (size_t)row * D_;
  f32x4 v0 = *(const f32x4*)(xr + t * 8);
  f32x4 v1 = *(const f32x4*)(xr + t * 8 + 4);
  float s = v0[0] + v0[1] + v0[2] + v0[3] + v1[0] + v1[1] + v1[2] + v1[3];
#pragma unroll
  for (int off = 1; off < 64; off <<= 1) s += __shfl_xor(s, off);
  __shared__ float red[4];
  if ((t & 63) == 0) red[t >> 6] = s;
  __syncthreads();
  const float mu = (red[0] + red[1] + red[2] + red[3]) * (1.0f / D_);
  const float CNS = (float)D_ / (float)(D_ - 1);
  f32x4 g0 = *(const f32x4*)(g + t * 8);
  f32x4 g1 = *(const f32x4*)(g + t * 8 + 4);
  f32x4 b0 = *(const f32x4*)(bb + t * 8);
  f32x4 b1 = *(const f32x4*)(bb + t * 8 + 4);
  f32x4 y0, y1;
  short8 yb;
#pragma unroll
  for (int i = 0; i < 4; i++) {
    y0[i] = g0[i] * (CNS * (v0[i] - mu)) + b0[i];
    y1[i] = g1[i] * (CNS * (v1[i] - mu)) + b1[i];
  }
#pragma unroll
  for (int i = 0; i < 4; i++) { yb[i] = (short)f2bf(y0[i]); yb[4 + i] = (short)f2bf(y1[i]); }
  float* orow = of + (size_t)row * D_;
  *(f32x4*)(orow + t * 8) = y0;
  *(f32x4*)(orow + t * 8 + 4) = y1;
  *(short8*)(ob + (size_t)row * D_ + t * 8) = yb;
}

// ---------------- l2norm q,k + head reorder; v convert ----------------
__global__ __launch_bounds__(256) void k_l2norm(const float* __restrict__ q,
                                                const float* __restrict__ k,
                                                const float* __restrict__ v,
                                                u16* __restrict__ qn,
                                                u16* __restrict__ kn,
                                                u16* __restrict__ vn) {
  const int gw = blockIdx.x * 4 + (threadIdx.x >> 6);
  const int l = threadIdx.x & 63;
  const int h = gw & (H_ - 1);
  const int s = (gw >> 4) & (S_ - 1);
  const int b = gw >> 14;
  const size_t src = ((size_t)(b * S_ + s)) * D_ + h * DH_ + l * 2;
  const size_t dst = (((size_t)(b * H_ + h)) * S_ + s) * DH_ + l * 2;
  {
    f32x2 xv = *(const f32x2*)(q + src);
    float ss = xv[0] * xv[0] + xv[1] * xv[1];
#pragma unroll
    for (int off = 1; off < 64; off <<= 1) ss += __shfl_xor(ss, off);
    float sc = 1.f / (sqrtf(ss) + 1e-6f);
    u16x2 o; o[0] = f2bf(xv[0] * sc); o[1] = f2bf(xv[1] * sc);
    *(u16x2*)(qn + dst) = o;
  }
  {
    f32x2 xv = *(const f32x2*)(k + src);
    float ss = xv[0] * xv[0] + xv[1] * xv[1];
#pragma unroll
    for (int off = 1; off < 64; off <<= 1) ss += __shfl_xor(ss, off);
    float sc = 1.f / (sqrtf(ss) + 1e-6f);
    u16x2 o; o[0] = f2bf(xv[0] * sc); o[1] = f2bf(xv[1] * sc);
    *(u16x2*)(kn + dst) = o;
  }
  {
    f32x2 xv = *(const f32x2*)(v + src);
    u16x2 o; o[0] = f2bf(xv[0]); o[1] = f2bf(xv[1]);
    *(u16x2*)(vn + dst) = o;
  }
}

// ============ 256x256 GEMM — half-tile staged, single counted vmcnt per K-tile ============
// C[M,N] = A[M,K]*Bt[N,K]^T. 512 thr = 8 waves (wr in {0,1}, wc in {0..3}), BK=64.
// LDS 128KB: 2 bufs x (A 256x64 | B 256x64) bf16, 128B rows, XOR swizzle
// byte ^= (row&7)<<4 (write side via pre-swizzled global source -> involution).
// Half-tile H(t,h) = {A rows h*128.., B rows h*128..} of K-tile t = 4 gload_lds/thread.
// Schedule (3 half-tiles in flight):
//   prologue: H(0,0) H(0,1) H(1,0); vmcnt(4); barrier
//   tile t: read B frags (both halves resident); phases q=0..3 (A-quarter q):
//     q==1: issue H(t+1,1)->buf^1; then mid-barrier (bounds drift: all half-0 reads done)
//     q==3: issue H(t+2,0)->buf   (safe: past mid-barrier all waves finished half-0 reads)
//   end: vmcnt(4) [retires H(t+1,0),H(t+1,1); leaves H(t+2,0)]; barrier
// vmcnt never drains to 0 mid-stream. All RAW/WAR fenced by vmcnt-then-barrier.
// EPI 0: outf=acc+bias ; 2: outb=bf16(gelu(acc+bias)) ; 3: outf=acc (raw partial)
template <int EPI>
__device__ __forceinline__ void gemm256_core(const u16* __restrict__ A,
                                             const u16* __restrict__ Bt,
                                             const float* __restrict__ bias,
                                             float* __restrict__ outf,
                                             u16* __restrict__ outb,
                                             int N, int K, int kbase, int nk,
                                             int m0, int n0) {
  __shared__ char lds[2][65536];  // [buf][A 32KB | B 32KB]
  const int t = threadIdx.x;
  const int l = t & 63, w = t >> 6;
  const int wr = w >> 2, wc = w & 3;
  const int l15 = l & 15, lhi = l >> 4;
  const int sw = (l15 & 7) << 4;
  // per-lane ds_read bases (ks=0/1); all per-phase offsets are compile-time imms
  const int ab0 = l15 * 128 + ((lhi * 16) ^ sw);
  const int ab1 = l15 * 128 + ((64 + lhi * 16) ^ sw);

  // stage half h of K-tile kt into buf kt&1 (4 loads: A j0,j1 then B j0,j1)
  auto stage = [&](int kt, int h) {
#pragma unroll
    for (int rj = 0; rj < 4; rj++) {
      const int region = rj >> 1, j = rj & 1;
      const int pl = h * 16384 + j * 8192 + t * 16;  // byte offset within region
      const int row = pl >> 7;
      const int scol = (pl & 127) ^ ((row & 7) << 4);
      const int grow = (region ? n0 : m0) + row;
      const char* src = (const char*)(region ? Bt : A) +
                        (size_t)grow * (size_t)(K * 2) +
                        (size_t)((kbase + kt * 64) * 2 + scol);
      gload16(src, &lds[kt & 1][region * 32768 + pl]);
    }
  };

  f32x4 acc[8][4] = {};

  stage(0, 0); stage(0, 1); stage(1, 0);
  asm volatile("s_waitcnt vmcnt(4)" ::: "memory");
  __builtin_amdgcn_s_barrier();
  __builtin_amdgcn_sched_barrier(0);

  for (int kt = 0; kt < nk; ++kt) {
    const char* base = &lds[kt & 1][0];
    const char* pA0 = base + wr * 4096 + ab0;
    const char* pA1 = base + wr * 4096 + ab1;
    const char* pB0 = base + 32768 + wc * 8192 + ab0;
    const char* pB1 = base + 32768 + wc * 8192 + ab1;
    short8 bf[4][2];
#pragma unroll
    for (int ni = 0; ni < 4; ni++) {
      bf[ni][0] = *(const short8*)(pB0 + ni * 2048);
      bf[ni][1] = *(const short8*)(pB1 + ni * 2048);
    }
#pragma unroll
    for (int q = 0; q < 4; q++) {
      short8 aq[2][2];
#pragma unroll
      for (int mi = 0; mi < 2; mi++) {
        aq[mi][0] = *(const short8*)(pA0 + q * 8192 + mi * 2048);
        aq[mi][1] = *(const short8*)(pA1 + q * 8192 + mi * 2048);
      }
      if (q == 1 && kt + 1 < nk) stage(kt + 1, 1);
      if (q == 3 && kt + 2 < nk) stage(kt + 2, 0);
      __builtin_amdgcn_s_setprio(1);
#pragma unroll
      for (int ks = 0; ks < 2; ks++)
#pragma unroll
        for (int mi = 0; mi < 2; mi++)
#pragma unroll
          for (int ni = 0; ni < 4; ni++)
            acc[q * 2 + mi][ni] = __builtin_amdgcn_mfma_f32_16x16x32_bf16(
                aq[mi][ks], bf[ni][ks], acc[q * 2 + mi][ni], 0, 0, 0);
      __builtin_amdgcn_s_setprio(0);
      if (q == 1) __builtin_amdgcn_s_barrier();  // drift bound for q==3 stage
    }
    if (kt + 1 < nk) {
      if (kt + 2 < nk) { asm volatile("s_waitcnt vmcnt(4)" ::: "memory"); }
      else             { asm volatile("s_waitcnt vmcnt(0)" ::: "memory"); }
      __builtin_amdgcn_s_barrier();
      __builtin_amdgcn_sched_barrier(0);
    }
  }

#pragma unroll
  for (int ni = 0; ni < 4; ni++) {
    const int col = n0 + wc * 64 + ni * 16 + l15;
    const float bcol = (EPI == 3) ? 0.f : bias[col];
#pragma unroll
    for (int ai = 0; ai < 8; ai++) {
      const int row = m0 + (ai >> 1) * 64 + wr * 32 + (ai & 1) * 16 + lhi * 4;
#pragma unroll
      for (int j = 0; j < 4; j++) {
        const float v = acc[ai][ni][j] + bcol;
        const size_t idx = (size_t)(row + j) * N + col;
        if (EPI == 0) outf[idx] = v;
        else if (EPI == 2) outb[idx] = f2bf(gelu_f(v));
        else outf[idx] = v;
      }
    }
  }
}

// natural blockIdx mapping: blocks sharing a B(weight)-panel sit bid%8 apart ->
// same XCD -> weight panel stays L2-resident. (Explicit swizzle measured WORSE:
// FETCH 49->135MB in r4/r5.)
__global__ __launch_bounds__(512, 2) void k_qkv256(const u16* A, const u16* W,
                                                   const float* b0, const float* b1,
                                                   const float* b2, float* o0, float* o1,
                                                   float* o2) {
  const int z = blockIdx.z;
  const u16* Bt = W + (size_t)z * 4194304;
  const float* bias = z == 0 ? b0 : (z == 1 ? b1 : b2);
  float* out = z == 0 ? o0 : (z == 1 ? o1 : o2);
  gemm256_core<0>(A, Bt, bias, out, nullptr, D_, D_, 0, 32,
                  blockIdx.y * 256, blockIdx.x * 256);
}

__global__ __launch_bounds__(512, 2) void k_ffn1_256(const u16* A, const u16* Bt,
                                                     const float* bias, u16* outb) {
  gemm256_core<2>(A, Bt, bias, nullptr, outb, F_, D_, 0, 32,
                  blockIdx.y * 256, blockIdx.x * 256);
}

__global__ __launch_bounds__(512, 2) void k_ffn2_256(const u16* A, const u16* Bt, float* P) {
  gemm256_core<3>(A, Bt, nullptr, P + (size_t)blockIdx.z * M_ * D_, nullptr, D_, F_,
                  blockIdx.z * 2048, 32, blockIdx.y * 256, blockIdx.x * 256);
}

// ---------------- 128x128 2-phase GEMM (o-proj: EPI1 residual) ----------------
__device__ __forceinline__ void gemm128_res(const u16* __restrict__ A,
                                            const u16* __restrict__ Bt,
                                            const float* __restrict__ bias,
                                            const float* __restrict__ res,
                                            const float* __restrict__ alpha,
                                            float* __restrict__ outf, int N, int K) {
  __shared__ u16 As[2][128 * 32];
  __shared__ u16 Bs[2][128 * 32];
  const int t = threadIdx.x;
  const int l = t & 63;
  const int w = t >> 6;
  const int wr = w >> 1, wc = w & 1;
  const int l15 = l & 15, lhi = l >> 4;
  const int m0 = blockIdx.y * 128, n0 = blockIdx.x * 128;
  f32x4 acc[4][4] = {};
  const int srow = t >> 2;
  const int scol = (t & 3) * 8;
  const u16* Ag = A + (size_t)(m0 + srow) * K + scol;
  const u16* Ag2 = Ag + (size_t)64 * K;
  const u16* Bg = Bt + (size_t)(n0 + srow) * K + scol;
  const u16* Bg2 = Bg + (size_t)64 * K;
  const int loff = t * 16;
  const int kiters = K / 32;

  gload16(Ag, (char*)As[0] + loff);
  gload16(Ag2, (char*)As[0] + 4096 + loff);
  gload16(Bg, (char*)Bs[0] + loff);
  gload16(Bg2, (char*)Bs[0] + 4096 + loff);
  __syncthreads();

  int cur = 0;
  for (int it = 0; it < kiters; ++it) {
    if (it + 1 < kiters) {
      const int k0 = (it + 1) * 32;
      char* dA = (char*)As[cur ^ 1] + loff;
      char* dB = (char*)Bs[cur ^ 1] + loff;
      gload16(Ag + k0, dA);
      gload16(Ag2 + k0, dA + 4096);
      gload16(Bg + k0, dB);
      gload16(Bg2 + k0, dB + 4096);
    }
    short8 af[4], bfr[4];
#pragma unroll
    for (int i = 0; i < 4; i++)
      af[i] = *(const short8*)(As[cur] + (wr * 64 + i * 16 + l15) * 32 + lhi * 8);
#pragma unroll
    for (int i = 0; i < 4; i++)
      bfr[i] = *(const short8*)(Bs[cur] + (wc * 64 + i * 16 + l15) * 32 + lhi * 8);
#pragma unroll
    for (int mi = 0; mi < 4; mi++)
#pragma unroll
      for (int ni = 0; ni < 4; ni++)
        acc[mi][ni] = __builtin_amdgcn_mfma_f32_16x16x32_bf16(af[mi], bfr[ni], acc[mi][ni], 0, 0, 0);
    __syncthreads();
    cur ^= 1;
  }
#pragma unroll
  for (int ni = 0; ni < 4; ni++) {
    const int col = n0 + wc * 64 + ni * 16 + l15;
    const float bcol = bias[col];
    const float alc = clipa(alpha[col]);
#pragma unroll
    for (int mi = 0; mi < 4; mi++) {
#pragma unroll
      for (int j = 0; j < 4; j++) {
        const int row = m0 + wr * 64 + mi * 16 + lhi * 4 + j;
        const size_t idx = (size_t)row * N + col;
        outf[idx] = res[idx] + alc * (acc[mi][ni][j] + bcol);
      }
    }
  }
}

__global__ __launch_bounds__(256) void k_oproj(const u16* A, const u16* Bt, const float* bias,
                                               const float* res, const float* alpha,
                                               float* outf) {
  gemm128_res(A, Bt, bias, res, alpha, outf, D_, D_);
}

// out = res + clip(alpha)*(sum_z P[z] + bias)
__global__ __launch_bounds__(256) void k_ffn2_combine(const float* __restrict__ P,
                                                      const float* __restrict__ bias,
                                                      const float* __restrict__ res,
                                                      const float* __restrict__ alpha,
                                                      float* __restrict__ out) {
  const int i = blockIdx.x * 256 + threadIdx.x;
  const size_t base = (size_t)i * 8;
  const int col = (int)(base & (D_ - 1));
  const size_t PS = (size_t)M_ * D_;
  f32x4 s0 = {}, s1 = {};
#pragma unroll
  for (int p = 0; p < 4; p++) {
    s0 += *(const f32x4*)(P + p * PS + base);
    s1 += *(const f32x4*)(P + p * PS + base + 4);
  }
  f32x4 b0 = *(const f32x4*)(bias + col);
  f32x4 b1 = *(const f32x4*)(bias + col + 4);
  f32x4 a0 = *(const f32x4*)(alpha + col);
  f32x4 a1 = *(const f32x4*)(alpha + col + 4);
  f32x4 r0 = *(const f32x4*)(res + base);
  f32x4 r1 = *(const f32x4*)(res + base + 4);
  f32x4 o0, o1;
#pragma unroll
  for (int j = 0; j < 4; j++) {
    o0[j] = r0[j] + clipa(a0[j]) * (s0[j] + b0[j]);
    o1[j] = r1[j] + clipa(a1[j]) * (s1[j] + b1[j]);
  }
  *(f32x4*)(out + base) = o0;
  *(f32x4*)(out + base + 4) = o1;
}

// ---------------- attention: cosine attn, causal, online softmax ----------------
__global__ __launch_bounds__(256) void k_attn(const u16* __restrict__ qn,
                                              const u16* __restrict__ kn,
                                              const u16* __restrict__ vn,
                                              const float* __restrict__ tau,
                                              const float* __restrict__ nu,
                                              u16* __restrict__ o) {
  __shared__ u16 Ks[64 * 128];   // row-major [kv][dh], XOR-swizzled
  __shared__ u16 Vt[128 * 64];   // transposed [dh][kv], XOR-swizzled
  __shared__ u16 Pl[4][16][72];  // per-wave P, +8 pad
  const int t = threadIdx.x;
  const int l = t & 63, w = t >> 6;
  const int l15 = l & 15, lhi = l >> 4;
  const int qt = blockIdx.x;
  const int bh = blockIdx.y;
  const int h = bh & (H_ - 1);
  const int b = bh >> 4;
  const size_t hoff = (size_t)bh * S_ * DH_;
  const u16* Qh = qn + hoff;
  const u16* Kh = kn + hoff;
  const u16* Vh = vn + hoff;
  const int q0 = qt * 64;
  const int r0 = q0 + w * 16;
  short8 qf[4];
#pragma unroll
  for (int kk = 0; kk < 4; kk++)
    qf[kk] = *(const short8*)(Qh + (size_t)(r0 + l15) * DH_ + kk * 32 + lhi * 8);
  const float taum = tau[h];
  float mrow[4], lrow[4];
  f32x4 oacc[8] = {};
#pragma unroll
  for (int j = 0; j < 4; j++) { mrow[j] = -1e30f; lrow[j] = 0.f; }

  for (int kv0 = 0; kv0 < q0 + 64; kv0 += 64) {
#pragma unroll
    for (int i = 0; i < 4; i++) {
      const int p = i * 4096 + t * 16;
      const int row = p >> 8;
      const int colb = p & 255;
      const int scolb = colb ^ ((row & 7) << 4);
      gload16((const char*)(Kh + (size_t)(kv0 + row) * DH_) + scolb, (char*)Ks + p);
    }
#pragma unroll
    for (int i = 0; i < 4; i++) {
      const int c0 = w * 8 + i * 32;
      const int r = l;
      short8 vv = *(const short8*)(Vh + (size_t)(kv0 + r) * DH_ + c0);
#pragma unroll
      for (int j = 0; j < 8; j++) {
        const int ba = ((c0 + j) * 128 + r * 2) ^ (((c0 + j) & 7) << 4);
        *(u16*)((char*)Vt + ba) = (u16)vv[j];
      }
    }
    __syncthreads();
    f32x4 st[4] = {};
#pragma unroll
    for (int ks = 0; ks < 4; ks++) {
#pragma unroll
      for (int ct = 0; ct < 4; ct++) {
        const int n = ct * 16 + l15;
        const int ka = (ks * 32 + lhi * 8) * 2;
        short8 kf = *(const short8*)((const char*)Ks + n * 256 + (ka ^ ((n & 7) << 4)));
        st[ct] = __builtin_amdgcn_mfma_f32_16x16x32_bf16(qf[ks], kf, st[ct], 0, 0, 0);
      }
    }
    float pm[4] = {-1e30f, -1e30f, -1e30f, -1e30f};
#pragma unroll
    for (int ct = 0; ct < 4; ct++) {
      const int col = kv0 + ct * 16 + l15;
#pragma unroll
      for (int j = 0; j < 4; j++) {
        const int row = r0 + lhi * 4 + j;
        float s = st[ct][j] * taum;
        s = (col <= row) ? s : -1e30f;
        st[ct][j] = s;
        pm[j] = fmaxf(pm[j], s);
      }
    }
#pragma unroll
    for (int j = 0; j < 4; j++) {
#pragma unroll
      for (int off = 1; off < 16; off <<= 1) pm[j] = fmaxf(pm[j], __shfl_xor(pm[j], off));
    }
    float scl[4], psum[4];
#pragma unroll
    for (int j = 0; j < 4; j++) {
      const float nm = fmaxf(mrow[j], pm[j]);
      scl[j] = __expf(mrow[j] - nm);
      mrow[j] = nm;
      psum[j] = 0.f;
    }
#pragma unroll
    for (int ct = 0; ct < 4; ct++) {
#pragma unroll
      for (int j = 0; j < 4; j++) {
        const float p = __expf(st[ct][j] - mrow[j]);
        psum[j] += p;
        Pl[w][lhi * 4 + j][ct * 16 + l15] = f2bf(p);
      }
    }
#pragma unroll
    for (int j = 0; j < 4; j++) {
#pragma unroll
      for (int off = 1; off < 16; off <<= 1) psum[j] += __shfl_xor(psum[j], off);
      lrow[j] = lrow[j] * scl[j] + psum[j];
    }
#pragma unroll
    for (int nt = 0; nt < 8; nt++) {
#pragma unroll
      for (int j = 0; j < 4; j++) oacc[nt][j] *= scl[j];
    }
#pragma unroll
    for (int ks2 = 0; ks2 < 2; ks2++) {
      short8 pa = *(const short8*)((const char*)&Pl[w][0][0] + l15 * 144 + ks2 * 64 + lhi * 16);
#pragma unroll
      for (int nt = 0; nt < 8; nt++) {
        const int n = nt * 16 + l15;
        const int ba = (n * 128 + (ks2 * 32 + lhi * 8) * 2) ^ ((n & 7) << 4);
        short8 vf = *(const short8*)((const char*)Vt + ba);
        oacc[nt] = __builtin_amdgcn_mfma_f32_16x16x32_bf16(pa, vf, oacc[nt], 0, 0, 0);
      }
    }
    __syncthreads();
  }
  const float num = nu[h];
  float rs[4];
#pragma unroll
  for (int j = 0; j < 4; j++) rs[j] = num / lrow[j];
#pragma unroll
  for (int nt = 0; nt < 8; nt++) {
    const int col = h * DH_ + nt * 16 + l15;
#pragma unroll
    for (int j = 0; j < 4; j++) {
      const int row = r0 + lhi * 4 + j;
      o[((size_t)b * S_ + row) * D_ + col] = f2bf(oacc[nt][j] * rs[j]);
    }
  }
}

// ---------------- launch ----------------
extern "C" void kernel_launch(void* const* d_in, const int* in_sizes, int n_in,
                              void* d_out, int out_size, void* d_ws, size_t ws_size,
                              hipStream_t stream) {
  const float* x    = (const float*)d_in[0];
  const float* ln1g = (const float*)d_in[1];
  const float* ln1b = (const float*)d_in[2];
  const float* wq   = (const float*)d_in[3];
  const float* bq   = (const float*)d_in[4];
  const float* wk   = (const float*)d_in[5];
  const float* bk   = (const float*)d_in[6];
  const float* wv   = (const float*)d_in[7];
  const float* bv   = (const float*)d_in[8];
  const float* wo   = (const float*)d_in[9];
  const float* bo   = (const float*)d_in[10];
  const float* tau  = (const float*)d_in[11];
  const float* nu   = (const float*)d_in[12];
  const float* al1  = (const float*)d_in[13];
  const float* ln2g = (const float*)d_in[14];
  const float* ln2b = (const float*)d_in[15];
  const float* w1   = (const float*)d_in[16];
  const float* b1   = (const float*)d_in[17];
  const float* w2   = (const float*)d_in[18];
  const float* b2   = (const float*)d_in[19];
  const float* al2  = (const float*)d_in[20];

  char* ws = (char*)d_ws;
  u16* WQ = (u16*)(ws + 0);
  u16* WO = (u16*)(ws + 25165824);
  u16* W1B = (u16*)(ws + 33554432);
  u16* W2B = (u16*)(ws + 67108864);
  float* AF = (float*)(ws + 100663296);   // centernorm1 f32
  u16*   AB = (u16*)(ws + 117440512);     // centernorm1 bf16
  float* QF = (float*)(ws + 125829120);
  float* KF = (float*)(ws + 142606336);
  float* VF = (float*)(ws + 159383552);
  u16* QN = (u16*)(ws + 176160768);
  u16* KN = (u16*)(ws + 184549376);
  u16* VN = (u16*)(ws + 192937984);
  // reuse after l2norm / attention:
  u16*   OB = (u16*)(ws + 125829120);     // attn out bf16 (over QF)
  u16*   MB = (u16*)(ws + 134217728);     // centernorm2 bf16 (over QF hi half)
  float* X1 = (float*)(ws + 142606336);   // residual1 f32 (over KF)
  float* MF2 = (float*)(ws + 159383552);  // centernorm2 f32 (over VF)
  u16*   HB = (u16*)(ws + 176160768);     // ffn hidden bf16 (over QN..)
  float* P4 = (float*)(ws + 0);           // ffn2 split-K partials, 4x16MB (over dead WQ..W1B)

  // weights -> bf16 (one kernel; dst region contiguous at ws+0)
  k_cvt_all<<<24576, 256, 0, stream>>>(wq, wk, wv, wo, w1, w2, WQ);

  // centernorm 1
  k_centernorm<<<M_, 256, 0, stream>>>(x, ln1g, ln1b, AF, AB);

  // qkv projections (WQ/WK/WV contiguous)
  k_qkv256<<<dim3(8, 8, 3), 512, 0, stream>>>(AB, WQ, bq, bk, bv, QF, KF, VF);

  // l2norm + head reorder
  k_l2norm<<<8192, 256, 0, stream>>>(QF, KF, VF, QN, KN, VN);

  // attention
  k_attn<<<dim3(S_ / 64, B_ * H_), 256, 0, stream>>>(QN, KN, VN, tau, nu, OB);

  // output projection + residual (x1 = a + a1*attn) — 128^2 2-phase
  k_oproj<<<dim3(16, 16), 256, 0, stream>>>(OB, WO, bo, AF, al1, X1);

  // centernorm 2
  k_centernorm<<<M_, 256, 0, stream>>>(X1, ln2g, ln2b, MF2, MB);

  // ffn1 (gelu -> bf16)
  k_ffn1_256<<<dim3(32, 8), 512, 0, stream>>>(MB, W1B, b1, HB);

  // ffn2 split-K=4 partials + combine (out = m + a2*(sum+bias))
  k_ffn2_256<<<dim3(8, 8, 4), 512, 0, stream>>>(HB, W2B, P4);
  k_ffn2_combine<<<2048, 256, 0, stream>>>(P4, b2, MF2, al2, (float*)d_out);
}